// Round 1
// 189.203 us; speedup vs baseline: 1.0712x; 1.0712x over previous
//
#include <hip/hip_runtime.h>
#include <hip/hip_bf16.h>

// Causal flash attention fwd. B=2,H=16,S=2048,D=128, fp32 io, bf16 MFMA.
// R4: v_cvt_pk_bf16_f32 for ALL fp32->bf16 (staging + P pack), exp2-domain
// softmax with raw v_exp_f32, defer-max rescale (THR=8), per-lane partial
// denominator, s_setprio around MFMA clusters. Tile structure/swizzles from R3.
constexpr int Bb = 2, Hh = 16, Ss = 2048, Dd = 128;
constexpr int BM = 64, BN = 64;
constexpr int NQT = Ss / BM;
// 1/sqrt(128) * log2(e): scores come out of QK^T already in log2 units.
constexpr float SCALE = 0.088388347648318447f * 1.4426950408889634f;

typedef __attribute__((ext_vector_type(8))) short bf16x8;
typedef __attribute__((ext_vector_type(4))) float f32x4;
typedef __attribute__((ext_vector_type(4))) int int4v;

__device__ __forceinline__ unsigned cvtpk(float lo, float hi) {
  unsigned r;
  asm("v_cvt_pk_bf16_f32 %0, %1, %2" : "=v"(r) : "v"(lo), "v"(hi));
  return r;                                    // [15:0]=bf16(lo) [31:16]=bf16(hi), RNE
}
__device__ __forceinline__ float exp2hw(float x) {
  float r;
  asm("v_exp_f32 %0, %1" : "=v"(r) : "v"(x));  // hardware exp2
  return r;
}
__device__ __forceinline__ float fcomp(float4 f, int j) {   // j is unroll-constant
  return j == 0 ? f.x : (j == 1 ? f.y : (j == 2 ? f.z : f.w));
}

__global__ __launch_bounds__(256, 2)
void fa_fwd_kernel(const float* __restrict__ q, const float* __restrict__ k,
                   const float* __restrict__ v, float* __restrict__ out) {
  // K tile row-major bf16: row=256B (16x16B blocks), block b at b^(row&15)
  __shared__ __align__(16) char Klds[BN * 256];    // 16 KB
  // V tile transposed Vt[d][key]: row=128B (8x16B blocks), block b at b^((d^(d>>3))&7)
  __shared__ __align__(16) char Vlds[Dd * 128];    // 16 KB

  const int tid = threadIdx.x;
  const int wave = tid >> 6, lane = tid & 63, quad = lane >> 4, l16 = lane & 15;
  const int bid = blockIdx.x;
  const int bh = bid & 31;
  const int qt = (NQT - 1) - (bid >> 5);           // heavy tiles first

  const float* qb = q + (size_t)bh * Ss * Dd;
  const float* kb = k + (size_t)bh * Ss * Dd;
  const float* vb = v + (size_t)bh * Ss * Dd;

  // ---- Q fragments (scale*log2e folded). Lane holds Q[qrow=wave*16+l16][d=32ks+8quad+j]
  bf16x8 qf[4];
  {
    const float* qr = qb + (size_t)(qt * BM + wave * 16 + l16) * Dd + quad * 8;
    #pragma unroll
    for (int ks = 0; ks < 4; ++ks) {
      float4 a = *(const float4*)(qr + ks * 32);
      float4 b = *(const float4*)(qr + ks * 32 + 4);
      int4v t;
      t[0] = (int)cvtpk(a.x * SCALE, a.y * SCALE);
      t[1] = (int)cvtpk(a.z * SCALE, a.w * SCALE);
      t[2] = (int)cvtpk(b.x * SCALE, b.y * SCALE);
      t[3] = (int)cvtpk(b.z * SCALE, b.w * SCALE);
      qf[ks] = __builtin_bit_cast(bf16x8, t);
    }
  }

  // ---- staging geometry (constant per thread)
  // K: thread owns 4 blocks: (row = krow0+16i, block kblk); loads 8 fp32, writes b128
  const int krow0 = tid >> 4;            // 0..15
  const int kblk  = tid & 15;            // block index = d/8
  const int kswz  = kblk ^ krow0;        // row&15 == krow0 for all i (row=krow0+16i)
  // V: thread owns 8keys x 4d micro-tile: kg = key-block, vdq*4 = d0
  const int vkg = tid >> 5;              // 0..7  (keys vkg*8 .. +7)
  const int vdq = tid & 31;              // d0 = vdq*4

  float4 ka[4], kc[4];                   // K prefetch: pair (ka[i],kc[i]) = 8 fp32
  float4 vr[8];                          // V prefetch: 8 key-rows x 4 d

  auto load_tiles = [&](int kt) {
    const float* Kg = kb + (size_t)(kt * BN) * Dd + kblk * 8;
    #pragma unroll
    for (int i = 0; i < 4; ++i) {
      ka[i] = *(const float4*)(Kg + (size_t)(krow0 + 16 * i) * Dd);
      kc[i] = *(const float4*)(Kg + (size_t)(krow0 + 16 * i) * Dd + 4);
    }
    const float* Vg = vb + (size_t)(kt * BN + vkg * 8) * Dd + vdq * 4;
    #pragma unroll
    for (int r = 0; r < 8; ++r)
      vr[r] = *(const float4*)(Vg + (size_t)r * Dd);
  };

  auto stage_tiles = [&]() {
    #pragma unroll
    for (int i = 0; i < 4; ++i) {
      int4v t;
      t[0] = (int)cvtpk(ka[i].x, ka[i].y);
      t[1] = (int)cvtpk(ka[i].z, ka[i].w);
      t[2] = (int)cvtpk(kc[i].x, kc[i].y);
      t[3] = (int)cvtpk(kc[i].z, kc[i].w);
      *(int4v*)(Klds + (krow0 + 16 * i) * 256 + kswz * 16) = t;
    }
    #pragma unroll
    for (int j = 0; j < 4; ++j) {
      int d = vdq * 4 + j;
      int f7 = (d ^ (d >> 3)) & 7;
      int4v t;
      t[0] = (int)cvtpk(fcomp(vr[0], j), fcomp(vr[1], j));
      t[1] = (int)cvtpk(fcomp(vr[2], j), fcomp(vr[3], j));
      t[2] = (int)cvtpk(fcomp(vr[4], j), fcomp(vr[5], j));
      t[3] = (int)cvtpk(fcomp(vr[6], j), fcomp(vr[7], j));
      *(int4v*)(Vlds + d * 128 + (vkg ^ f7) * 16) = t;
    }
  };

  f32x4 o[8];
  #pragma unroll
  for (int i = 0; i < 8; ++i) o[i] = (f32x4)(0.0f);
  float mrow = -3.0e38f, lrow = 0.0f;    // per-lane; lrow is a PARTIAL sum (this lane's keys)

  load_tiles(0);
  stage_tiles();

  const int hi2 = quad >> 1;
  const int srcbase = (l16 + 32 * (quad & 1)) * 4;   // bpermute byte base

  for (int kt = 0; kt <= qt; ++kt) {
    __syncthreads();                     // tile kt visible
    const bool more = kt < qt;
    if (more) load_tiles(kt + 1);        // issue prefetch, no wait until loop end

    // ---- S^T = K Q^T : acc[nt][r] = S[qrow=l16][key=kt*64 + nt*16+quad*4+r]
    f32x4 acc[4];
    #pragma unroll
    for (int nt = 0; nt < 4; ++nt) acc[nt] = (f32x4)(0.0f);
    __builtin_amdgcn_s_setprio(1);
    #pragma unroll
    for (int ks = 0; ks < 4; ++ks) {
      #pragma unroll
      for (int nt = 0; nt < 4; ++nt) {
        int row = nt * 16 + l16;
        int bswz = (ks * 4 + quad) ^ l16;
        bf16x8 kf = *(const bf16x8*)(Klds + row * 256 + bswz * 16);
        acc[nt] = __builtin_amdgcn_mfma_f32_16x16x32_bf16(kf, qf[ks], acc[nt], 0, 0, 0);
      }
    }
    __builtin_amdgcn_s_setprio(0);

    // ---- causal mask on diagonal tile
    if (kt == qt) {
      #pragma unroll
      for (int nt = 0; nt < 4; ++nt)
        #pragma unroll
        for (int r = 0; r < 4; ++r)
          if (nt * 16 + quad * 4 + r > wave * 16 + l16) acc[nt][r] = -1.0e30f;
    }

    // ---- online softmax (log2 domain; row along regs; max-reduce over 4 lanes sharing l16)
    float mx = acc[0][0];
    #pragma unroll
    for (int nt = 0; nt < 4; ++nt)
      #pragma unroll
      for (int r = 0; r < 4; ++r) mx = fmaxf(mx, acc[nt][r]);
    mx = fmaxf(mx, __shfl_xor(mx, 16, 64));
    mx = fmaxf(mx, __shfl_xor(mx, 32, 64));

    // defer-max: only rescale when the row max grew by > 8 (p bounded by 2^8)
    if (!__all(mx - mrow <= 8.0f)) {
      float mn = fmaxf(mrow, mx);
      float alpha = exp2hw(mrow - mn);
      mrow = mn;
      lrow *= alpha;
      #pragma unroll
      for (int r = 0; r < 4; ++r) {
        int src = (lane & 48) | (quad * 4 + r);
        float ar = __shfl(alpha, src, 64);
        #pragma unroll
        for (int dt = 0; dt < 8; ++dt) o[dt][r] *= ar;
      }
    }

    float rs = 0.f;
    #pragma unroll
    for (int nt = 0; nt < 4; ++nt)
      #pragma unroll
      for (int r = 0; r < 4; ++r) {
        float p = exp2hw(acc[nt][r] - mrow);
        acc[nt][r] = p; rs += p;
      }
    lrow += rs;                          // per-lane partial; reduced in epilogue

    // pack P: pk[nt][pp] = keys nt*16+quad*4+{2pp,2pp+1} (bf16 pair)
    unsigned pk0_0 = cvtpk(acc[0][0], acc[0][1]), pk0_1 = cvtpk(acc[0][2], acc[0][3]);
    unsigned pk1_0 = cvtpk(acc[1][0], acc[1][1]), pk1_1 = cvtpk(acc[1][2], acc[1][3]);
    unsigned pk2_0 = cvtpk(acc[2][0], acc[2][1]), pk2_1 = cvtpk(acc[2][2], acc[2][3]);
    unsigned pk3_0 = cvtpk(acc[3][0], acc[3][1]), pk3_1 = cvtpk(acc[3][2], acc[3][3]);

    // ---- P A-fragments via bpermute among 4 lanes sharing l16
    bf16x8 pf[2];
    {
      int4v p0, p1;
      #pragma unroll
      for (int jp = 0; jp < 4; ++jp) {
        int srcb = srcbase + 64 * (jp >> 1);
        int a0 = __builtin_amdgcn_ds_bpermute(srcb, (int)((jp & 1) ? pk0_1 : pk0_0));
        int a1 = __builtin_amdgcn_ds_bpermute(srcb, (int)((jp & 1) ? pk1_1 : pk1_0));
        int a2 = __builtin_amdgcn_ds_bpermute(srcb, (int)((jp & 1) ? pk2_1 : pk2_0));
        int a3 = __builtin_amdgcn_ds_bpermute(srcb, (int)((jp & 1) ? pk3_1 : pk3_0));
        p0[jp] = hi2 ? a1 : a0;
        p1[jp] = hi2 ? a3 : a2;
      }
      pf[0] = __builtin_bit_cast(bf16x8, p0);
      pf[1] = __builtin_bit_cast(bf16x8, p1);
    }

    // ---- O += P V
    __builtin_amdgcn_s_setprio(1);
    #pragma unroll
    for (int ks2 = 0; ks2 < 2; ++ks2) {
      #pragma unroll
      for (int dt = 0; dt < 8; ++dt) {
        int row = dt * 16 + l16;
        int f7 = (row ^ (row >> 3)) & 7;
        int bswz = (ks2 * 4 + quad) ^ f7;
        bf16x8 vf = *(const bf16x8*)(Vlds + row * 128 + bswz * 16);
        o[dt] = __builtin_amdgcn_mfma_f32_16x16x32_bf16(pf[ks2], vf, o[dt], 0, 0, 0);
      }
    }
    __builtin_amdgcn_s_setprio(0);

    if (more) { __syncthreads(); stage_tiles(); }   // prefetch waits resolve here
  }

  // ---- epilogue: reduce partial denominators, then O / l
  lrow += __shfl_xor(lrow, 16, 64);
  lrow += __shfl_xor(lrow, 32, 64);
  float linv[4];
  #pragma unroll
  for (int r = 0; r < 4; ++r) {
    int src = (lane & 48) | (quad * 4 + r);
    linv[r] = 1.0f / __shfl(lrow, src, 64);
  }
  float* ob = out + ((size_t)bh * Ss + qt * BM + wave * 16) * Dd;
  #pragma unroll
  for (int dt = 0; dt < 8; ++dt)
    #pragma unroll
    for (int r = 0; r < 4; ++r)
      ob[(quad * 4 + r) * Dd + dt * 16 + l16] = o[dt][r] * linv[r];
}

extern "C" void kernel_launch(void* const* d_in, const int* in_sizes, int n_in,
                              void* d_out, int out_size, void* d_ws, size_t ws_size,
                              hipStream_t stream) {
  const float* q = (const float*)d_in[0];
  const float* k = (const float*)d_in[1];
  const float* v = (const float*)d_in[2];
  float* out = (float*)d_out;
  dim3 grid(Bb * Hh * NQT);   // 1024
  dim3 block(256);
  hipLaunchKernelGGL(fa_fwd_kernel, grid, block, 0, stream, q, k, v, out);
}